// Round 8
// baseline (512.394 us; speedup 1.0000x reference)
//
#include <hip/hip_runtime.h>
#include <math.h>

using bf_t = unsigned short;
typedef short s16x4 __attribute__((ext_vector_type(4)));
typedef short s16x8 __attribute__((ext_vector_type(8)));
typedef float f32x4 __attribute__((ext_vector_type(4)));

__device__ __forceinline__ bf_t f2bf(float f) {
  unsigned u = __float_as_uint(f);
  u += 0x7FFFu + ((u >> 16) & 1u);
  return (bf_t)(u >> 16);
}
__device__ __forceinline__ float bf2f(bf_t h) {
  return __uint_as_float(((unsigned)h) << 16);
}

// Single contiguous 16B fragment load. k-slot mapping is k = kg*8..kg*8+7;
// any bijective k-permutation cancels between the A and B operands of the
// same MFMA as long as both use this loader (they all do).
__device__ __forceinline__ s16x8 ld_frag(const bf_t* p) {
  return *(const s16x8*)p;
}

#define MFMA(A, B, C) __builtin_amdgcn_mfma_f32_16x16x32_bf16((A), (B), (C), 0, 0, 0)

// ---------------------------------------------------------------------------
// fp32 -> bf16 conversion (4 elems / thread)
// ---------------------------------------------------------------------------
__global__ void cvt_kernel(const float* __restrict__ in, bf_t* __restrict__ out, int n4) {
  int i = blockIdx.x * blockDim.x + threadIdx.x;
  if (i >= n4) return;
  float4 v = ((const float4*)in)[i];
  ushort4 o;
  o.x = f2bf(v.x); o.y = f2bf(v.y); o.z = f2bf(v.z); o.w = f2bf(v.w);
  ((ushort4*)out)[i] = o;
}

// ---------------------------------------------------------------------------
// bf16 GEMM: C[M][N] = A[M][K] * Bw[N][K]^T  (both operands K-contiguous)
// 128x128 tile, 4 waves (2x2), each wave 64x64 = 4x4 frags of 16x16x32 MFMA.
// EPI=0: scatter QKV (N=3072 concat) with V transposed.  EPI=1: fp32 out.
// ---------------------------------------------------------------------------
template <int EPI>
__global__ __launch_bounds__(256) void gemm_kernel(
    const bf_t* __restrict__ A, const bf_t* __restrict__ Bw,
    float* __restrict__ Cf,
    bf_t* __restrict__ Qb, bf_t* __restrict__ Kb, bf_t* __restrict__ Vt,
    int M, int N, int K) {
  constexpr int BKP = 40;  // 32 + pad -> 80B row stride, 16B aligned
  __shared__ bf_t As[128 * BKP];
  __shared__ bf_t Bs[128 * BKP];
  const int t = threadIdx.x;
  const int lane = t & 63;
  const int w = t >> 6;
  const int wr = w >> 1, wc = w & 1;
  const int col = lane & 15;
  const int kg = lane >> 4;
  const int m0 = blockIdx.y * 128;
  const int n0 = blockIdx.x * 128;

  f32x4 acc[4][4] = {};

  for (int k0 = 0; k0 < K; k0 += 32) {
#pragma unroll
    for (int p = 0; p < 2; ++p) {
      int idx = t + p * 256;
      int row = idx >> 2;
      int kk = (idx & 3) << 3;
      *(s16x8*)&As[row * BKP + kk] = *(const s16x8*)&A[(size_t)(m0 + row) * K + k0 + kk];
      *(s16x8*)&Bs[row * BKP + kk] = *(const s16x8*)&Bw[(size_t)(n0 + row) * K + k0 + kk];
    }
    __syncthreads();
    s16x8 af[4], bfg[4];
#pragma unroll
    for (int mi = 0; mi < 4; ++mi)
      af[mi] = ld_frag(&As[(wr * 64 + mi * 16 + col) * BKP + kg * 8]);
#pragma unroll
    for (int ni = 0; ni < 4; ++ni)
      bfg[ni] = ld_frag(&Bs[(wc * 64 + ni * 16 + col) * BKP + kg * 8]);
#pragma unroll
    for (int mi = 0; mi < 4; ++mi)
#pragma unroll
      for (int ni = 0; ni < 4; ++ni)
        acc[mi][ni] = MFMA(af[mi], bfg[ni], acc[mi][ni]);
    __syncthreads();
  }

#pragma unroll
  for (int mi = 0; mi < 4; ++mi)
#pragma unroll
    for (int ni = 0; ni < 4; ++ni)
#pragma unroll
      for (int r = 0; r < 4; ++r) {
        int gm = m0 + wr * 64 + mi * 16 + kg * 4 + r;
        int gn = n0 + wc * 64 + ni * 16 + col;
        float v = acc[mi][ni][r];
        if constexpr (EPI == 0) {
          int which = gn >> 10;
          int wn = gn & 1023;
          int h = wn >> 6, d = wn & 63;
          int b = gm >> 11, s = gm & 2047;
          size_t hb = (size_t)(b * 16 + h);
          if (which == 0)
            Qb[(hb * 2048 + s) * 64 + d] = f2bf(v);
          else if (which == 1)
            Kb[(hb * 2048 + s) * 64 + d] = f2bf(v);
          else
            Vt[(hb * 64 + d) * 2048 + s] = f2bf(v);
        } else {
          Cf[(size_t)gm * N + gn] = v;
        }
      }
}

// ---------------------------------------------------------------------------
// RoPE on Q and K in-place.
// ---------------------------------------------------------------------------
__global__ void rope_kernel(bf_t* __restrict__ Qb, bf_t* __restrict__ Kb,
                            const int* __restrict__ pos, int total) {
  int i = blockIdx.x * blockDim.x + threadIdx.x;
  if (i >= total) return;
  int ip = i & 31;
  int s = (i >> 5) & 2047;
  int bh = i >> 16;  // b*16 + h
  int b = bh >> 4;
  float p = (float)pos[b * 2048 + s];
  float ang = p * exp2f(-(float)ip * 0.41524101186f);
  float sv, cv;
  sincosf(ang, &sv, &cv);
  size_t base = ((size_t)bh * 2048 + s) * 64 + ip * 2;
  {
    unsigned u = *(const unsigned*)&Qb[base];
    float x1 = bf2f((bf_t)(u & 0xFFFF)), x2 = bf2f((bf_t)(u >> 16));
    unsigned o = (unsigned)f2bf(x1 * cv - x2 * sv) | ((unsigned)f2bf(x1 * sv + x2 * cv) << 16);
    *(unsigned*)&Qb[base] = o;
  }
  {
    unsigned u = *(const unsigned*)&Kb[base];
    float x1 = bf2f((bf_t)(u & 0xFFFF)), x2 = bf2f((bf_t)(u >> 16));
    unsigned o = (unsigned)f2bf(x1 * cv - x2 * sv) | ((unsigned)f2bf(x1 * sv + x2 * cv) << 16);
    *(unsigned*)&Kb[base] = o;
  }
}

// ---------------------------------------------------------------------------
// Causal flash attention, in-block split-KV.
// 4 waves / block; all waves own the SAME 64 q-rows; wave w processes k-tiles
// kb = w*32 + j*128 with private online-softmax state; merge via LDS at end.
// Heaviest q-blocks launch first (reversed blockIdx.x) for load balance.
// ---------------------------------------------------------------------------
__global__ __launch_bounds__(256) void attn_kernel(const bf_t* __restrict__ Qb,
                                                   const bf_t* __restrict__ Kb,
                                                   const bf_t* __restrict__ Vt,
                                                   bf_t* __restrict__ AO) {
  const int t = threadIdx.x;
  const int lane = t & 63;
  const int w = t >> 6;
  const int col = lane & 15;
  const int kg = lane >> 4;
  const int bh = blockIdx.y;
  const int q0 = ((int)gridDim.x - 1 - (int)blockIdx.x) * 64;
  const bf_t* Qp = Qb + (size_t)bh * 2048 * 64;
  const bf_t* Kp = Kb + (size_t)bh * 2048 * 64;
  const bf_t* Vp = Vt + (size_t)bh * 64 * 2048;

  // LDS layout: [0,20480) per-wave Pl (4 x 64x40 bf16), overlaid after the
  // k-loop by ocomb f32[64][65] (16640 B). [20480,21504) mw f32[4][64].
  // [21504,22528) lw f32[4][64].
  __shared__ char sh[22528];
  bf_t* Plw = (bf_t*)sh + w * 2560;
  float* ocomb = (float*)sh;                 // [64][65]
  float* mw = (float*)(sh + 20480);          // [4][64]
  float* lw = (float*)(sh + 21504);          // [4][64]

  s16x8 qf[4][2];
#pragma unroll
  for (int mi = 0; mi < 4; ++mi)
#pragma unroll
    for (int ks = 0; ks < 2; ++ks)
      qf[mi][ks] = ld_frag(Qp + (size_t)(q0 + mi * 16 + col) * 64 + ks * 32 + kg * 8);

  f32x4 o[4][4] = {};
  float mrun[4][4], lrun[4][4];
#pragma unroll
  for (int mi = 0; mi < 4; ++mi)
#pragma unroll
    for (int r = 0; r < 4; ++r) {
      mrun[mi][r] = -INFINITY;
      lrun[mi][r] = 0.0f;
    }

  for (int kb = w * 32; kb < q0 + 64; kb += 128) {
    s16x8 kf[2][2];
#pragma unroll
    for (int nk = 0; nk < 2; ++nk)
#pragma unroll
      for (int ks = 0; ks < 2; ++ks)
        kf[nk][ks] = ld_frag(Kp + (size_t)(kb + nk * 16 + col) * 64 + ks * 32 + kg * 8);

    f32x4 sc[4][2] = {};
#pragma unroll
    for (int mi = 0; mi < 4; ++mi)
#pragma unroll
      for (int nk = 0; nk < 2; ++nk)
#pragma unroll
        for (int ks = 0; ks < 2; ++ks)
          sc[mi][nk] = MFMA(qf[mi][ks], kf[nk][ks], sc[mi][nk]);

    const int k0g = kb + col, k1g = kb + 16 + col;
#pragma unroll
    for (int mi = 0; mi < 4; ++mi)
#pragma unroll
      for (int r = 0; r < 4; ++r) {
        int qg = q0 + mi * 16 + kg * 4 + r;
        float s0 = (k0g <= qg) ? sc[mi][0][r] * 0.125f : -INFINITY;
        float s1 = (k1g <= qg) ? sc[mi][1][r] * 0.125f : -INFINITY;
        float mx = fmaxf(s0, s1);
        mx = fmaxf(mx, __shfl_xor(mx, 1));
        mx = fmaxf(mx, __shfl_xor(mx, 2));
        mx = fmaxf(mx, __shfl_xor(mx, 4));
        mx = fmaxf(mx, __shfl_xor(mx, 8));
        float mold = mrun[mi][r];
        float mn = fmaxf(mold, mx);
        // mn can be -inf when this wave's tile is fully masked for this row
        // (split-KV start offset). Clamp the exp base so exp(-inf - mnc) = 0,
        // never exp(nan).
        float mnc = fmaxf(mn, -1e30f);
        float a = __expf(mold - mnc);
        float e0 = __expf(s0 - mnc);
        float e1 = __expf(s1 - mnc);
        sc[mi][0][r] = e0;
        sc[mi][1][r] = e1;
        float rs = e0 + e1;
        rs += __shfl_xor(rs, 1);
        rs += __shfl_xor(rs, 2);
        rs += __shfl_xor(rs, 4);
        rs += __shfl_xor(rs, 8);
        lrun[mi][r] = lrun[mi][r] * a + rs;
        mrun[mi][r] = mn;
#pragma unroll
        for (int ni = 0; ni < 4; ++ni) o[mi][ni][r] *= a;
      }

    // P -> bf16 transpose through wave-private LDS (no barrier needed: the
    // compiler's lgkmcnt waits order same-wave ds ops through the MFMA uses).
#pragma unroll
    for (int mi = 0; mi < 4; ++mi)
#pragma unroll
      for (int nk = 0; nk < 2; ++nk)
#pragma unroll
        for (int r = 0; r < 4; ++r)
          Plw[(mi * 16 + kg * 4 + r) * 40 + nk * 16 + col] = f2bf(sc[mi][nk][r]);

    s16x8 pa[4], vf[4];
#pragma unroll
    for (int mi = 0; mi < 4; ++mi) pa[mi] = ld_frag(&Plw[(mi * 16 + col) * 40 + kg * 8]);
#pragma unroll
    for (int ni = 0; ni < 4; ++ni)
      vf[ni] = ld_frag(Vp + (size_t)(ni * 16 + col) * 2048 + kb + kg * 8);
#pragma unroll
    for (int mi = 0; mi < 4; ++mi)
#pragma unroll
      for (int ni = 0; ni < 4; ++ni) o[mi][ni] = MFMA(pa[mi], vf[ni], o[mi][ni]);
  }

  // ---- merge the 4 waves' partial (m, l, O) ----
  // stats region does not overlap any wave's Pl, so writing before the
  // barrier is safe even while other waves still loop.
  if (col == 0) {
#pragma unroll
    for (int mi = 0; mi < 4; ++mi)
#pragma unroll
      for (int r = 0; r < 4; ++r) {
        int row = mi * 16 + kg * 4 + r;
        mw[w * 64 + row] = mrun[mi][r];
        lw[w * 64 + row] = lrun[mi][r];
      }
  }
  __syncthreads();  // all k-loops done; Pl dead; stats visible

  // zero the f32 combine buffer (overlays Pl)
  for (int i = t; i < 64 * 65; i += 256) ocomb[i] = 0.0f;
  __syncthreads();

  // every wave atomically accumulates its scaled O (static reg indexing only)
#pragma unroll
  for (int mi = 0; mi < 4; ++mi)
#pragma unroll
    for (int r = 0; r < 4; ++r) {
      int row = mi * 16 + kg * 4 + r;
      float ms = fmaxf(fmaxf(mw[row], mw[64 + row]), fmaxf(mw[128 + row], mw[192 + row]));
      float mo = mrun[mi][r];
      float s = (mo == -INFINITY) ? 0.0f : __expf(mo - ms);
#pragma unroll
      for (int ni = 0; ni < 4; ++ni)
        atomicAdd(&ocomb[row * 65 + ni * 16 + col], o[mi][ni][r] * s);
    }
  __syncthreads();

  // output: wave w writes row stripe [16w, 16w+16)
  const int b = bh >> 4, h = bh & 15;
#pragma unroll
  for (int r = 0; r < 4; ++r) {
    int row = w * 16 + kg * 4 + r;
    float ms = fmaxf(fmaxf(mw[row], mw[64 + row]), fmaxf(mw[128 + row], mw[192 + row]));
    float ls = 0.0f;
#pragma unroll
    for (int w2 = 0; w2 < 4; ++w2) {
      float mv = mw[w2 * 64 + row];
      ls += (mv == -INFINITY) ? 0.0f : lw[w2 * 64 + row] * __expf(mv - ms);
    }
    float inv = 1.0f / ls;
    int qg = q0 + row;
#pragma unroll
    for (int ni = 0; ni < 4; ++ni)
      AO[((size_t)b * 2048 + qg) * 1024 + h * 64 + ni * 16 + col] =
          f2bf(ocomb[row * 65 + ni * 16 + col] * inv);
  }
}

// ---------------------------------------------------------------------------
extern "C" void kernel_launch(void* const* d_in, const int* in_sizes, int n_in,
                              void* d_out, int out_size, void* d_ws, size_t ws_size,
                              hipStream_t stream) {
  const float* x = (const float*)d_in[0];
  const int* pos = (const int*)d_in[1];
  const float* Wq = (const float*)d_in[2];
  const float* Wk = (const float*)d_in[3];
  const float* Wv = (const float*)d_in[4];
  const float* Wo = (const float*)d_in[5];
  float* out = (float*)d_out;

  char* ws = (char*)d_ws;
  bf_t* xb    = (bf_t*)(ws);                 //  8,388,608 B  [4096][1024]
  bf_t* Wqkvb = (bf_t*)(ws + 8388608);       //  6,291,456 B  [3072][1024]
  bf_t* Wob   = (bf_t*)(ws + 14680064);      //  2,097,152 B  [1024][1024]
  bf_t* Qb    = (bf_t*)(ws + 16777216);      //  8,388,608 B  [2][16][2048][64]
  bf_t* Kb    = (bf_t*)(ws + 25165824);      //  8,388,608 B  [2][16][2048][64]
  bf_t* Vt    = (bf_t*)(ws + 33554432);      //  8,388,608 B  [2][16][64][2048]
  bf_t* AO    = (bf_t*)(ws + 41943040);      //  8,388,608 B  [4096][1024]

  cvt_kernel<<<4096, 256, 0, stream>>>(x, xb, 1048576);
  cvt_kernel<<<1024, 256, 0, stream>>>(Wq, Wqkvb, 262144);
  cvt_kernel<<<1024, 256, 0, stream>>>(Wk, Wqkvb + 1048576, 262144);
  cvt_kernel<<<1024, 256, 0, stream>>>(Wv, Wqkvb + 2097152, 262144);
  cvt_kernel<<<1024, 256, 0, stream>>>(Wo, Wob, 262144);

  gemm_kernel<0><<<dim3(24, 32), 256, 0, stream>>>(xb, Wqkvb, nullptr, Qb, Kb, Vt,
                                                   4096, 3072, 1024);
  rope_kernel<<<8192, 256, 0, stream>>>(Qb, Kb, pos, 2097152);
  attn_kernel<<<dim3(32, 32), 256, 0, stream>>>(Qb, Kb, Vt, AO);
  gemm_kernel<1><<<dim3(8, 32), 256, 0, stream>>>(AO, Wob, out, nullptr, nullptr, nullptr,
                                                  4096, 1024, 1024);
}

// Round 9
// 341.188 us; speedup vs baseline: 1.5018x; 1.5018x over previous
//
#include <hip/hip_runtime.h>
#include <math.h>

using bf_t = unsigned short;
typedef short s16x4 __attribute__((ext_vector_type(4)));
typedef short s16x8 __attribute__((ext_vector_type(8)));
typedef float f32x4 __attribute__((ext_vector_type(4)));

__device__ __forceinline__ bf_t f2bf(float f) {
  unsigned u = __float_as_uint(f);
  u += 0x7FFFu + ((u >> 16) & 1u);
  return (bf_t)(u >> 16);
}
__device__ __forceinline__ float bf2f(bf_t h) {
  return __uint_as_float(((unsigned)h) << 16);
}

// Single contiguous 16B fragment load. k-slot mapping is k = kg*8..kg*8+7;
// any bijective k-permutation cancels between the A and B operands of the
// same MFMA as long as both use this loader (they all do, incl. the P LDS
// round-trip: written [row][key], read back with the same convention).
__device__ __forceinline__ s16x8 ld_frag(const bf_t* p) {
  return *(const s16x8*)p;
}

#define MFMA(A, B, C) __builtin_amdgcn_mfma_f32_16x16x32_bf16((A), (B), (C), 0, 0, 0)

// ---------------------------------------------------------------------------
// fp32 -> bf16 conversion (4 elems / thread)
// ---------------------------------------------------------------------------
__global__ void cvt_kernel(const float* __restrict__ in, bf_t* __restrict__ out, int n4) {
  int i = blockIdx.x * blockDim.x + threadIdx.x;
  if (i >= n4) return;
  float4 v = ((const float4*)in)[i];
  ushort4 o;
  o.x = f2bf(v.x); o.y = f2bf(v.y); o.z = f2bf(v.z); o.w = f2bf(v.w);
  ((ushort4*)out)[i] = o;
}

// ---------------------------------------------------------------------------
// bf16 GEMM: C[M][N] = A[M][K] * Bw[N][K]^T  (both operands K-contiguous)
// 128x128 tile, 4 waves (2x2), each wave 64x64 = 4x4 frags of 16x16x32 MFMA.
// EPI=0: scatter QKV (N=3072 concat) with V transposed.  EPI=1: fp32 out.
// ---------------------------------------------------------------------------
template <int EPI>
__global__ __launch_bounds__(256) void gemm_kernel(
    const bf_t* __restrict__ A, const bf_t* __restrict__ Bw,
    float* __restrict__ Cf,
    bf_t* __restrict__ Qb, bf_t* __restrict__ Kb, bf_t* __restrict__ Vt,
    int M, int N, int K) {
  constexpr int BKP = 40;  // 32 + pad -> 80B row stride, 16B aligned
  __shared__ bf_t As[128 * BKP];
  __shared__ bf_t Bs[128 * BKP];
  const int t = threadIdx.x;
  const int lane = t & 63;
  const int w = t >> 6;
  const int wr = w >> 1, wc = w & 1;
  const int col = lane & 15;
  const int kg = lane >> 4;
  const int m0 = blockIdx.y * 128;
  const int n0 = blockIdx.x * 128;

  f32x4 acc[4][4] = {};

  for (int k0 = 0; k0 < K; k0 += 32) {
#pragma unroll
    for (int p = 0; p < 2; ++p) {
      int idx = t + p * 256;
      int row = idx >> 2;
      int kk = (idx & 3) << 3;
      *(s16x8*)&As[row * BKP + kk] = *(const s16x8*)&A[(size_t)(m0 + row) * K + k0 + kk];
      *(s16x8*)&Bs[row * BKP + kk] = *(const s16x8*)&Bw[(size_t)(n0 + row) * K + k0 + kk];
    }
    __syncthreads();
    s16x8 af[4], bfg[4];
#pragma unroll
    for (int mi = 0; mi < 4; ++mi)
      af[mi] = ld_frag(&As[(wr * 64 + mi * 16 + col) * BKP + kg * 8]);
#pragma unroll
    for (int ni = 0; ni < 4; ++ni)
      bfg[ni] = ld_frag(&Bs[(wc * 64 + ni * 16 + col) * BKP + kg * 8]);
#pragma unroll
    for (int mi = 0; mi < 4; ++mi)
#pragma unroll
      for (int ni = 0; ni < 4; ++ni)
        acc[mi][ni] = MFMA(af[mi], bfg[ni], acc[mi][ni]);
    __syncthreads();
  }

#pragma unroll
  for (int mi = 0; mi < 4; ++mi)
#pragma unroll
    for (int ni = 0; ni < 4; ++ni)
#pragma unroll
      for (int r = 0; r < 4; ++r) {
        int gm = m0 + wr * 64 + mi * 16 + kg * 4 + r;
        int gn = n0 + wc * 64 + ni * 16 + col;
        float v = acc[mi][ni][r];
        if constexpr (EPI == 0) {
          int which = gn >> 10;
          int wn = gn & 1023;
          int h = wn >> 6, d = wn & 63;
          int b = gm >> 11, s = gm & 2047;
          size_t hb = (size_t)(b * 16 + h);
          if (which == 0)
            Qb[(hb * 2048 + s) * 64 + d] = f2bf(v);
          else if (which == 1)
            Kb[(hb * 2048 + s) * 64 + d] = f2bf(v);
          else
            Vt[(hb * 64 + d) * 2048 + s] = f2bf(v);
        } else {
          Cf[(size_t)gm * N + gn] = v;
        }
      }
}

// ---------------------------------------------------------------------------
// RoPE on Q and K in-place.
// ---------------------------------------------------------------------------
__global__ void rope_kernel(bf_t* __restrict__ Qb, bf_t* __restrict__ Kb,
                            const int* __restrict__ pos, int total) {
  int i = blockIdx.x * blockDim.x + threadIdx.x;
  if (i >= total) return;
  int ip = i & 31;
  int s = (i >> 5) & 2047;
  int bh = i >> 16;  // b*16 + h
  int b = bh >> 4;
  float p = (float)pos[b * 2048 + s];
  float ang = p * exp2f(-(float)ip * 0.41524101186f);
  float sv, cv;
  sincosf(ang, &sv, &cv);
  size_t base = ((size_t)bh * 2048 + s) * 64 + ip * 2;
  {
    unsigned u = *(const unsigned*)&Qb[base];
    float x1 = bf2f((bf_t)(u & 0xFFFF)), x2 = bf2f((bf_t)(u >> 16));
    unsigned o = (unsigned)f2bf(x1 * cv - x2 * sv) | ((unsigned)f2bf(x1 * sv + x2 * cv) << 16);
    *(unsigned*)&Qb[base] = o;
  }
  {
    unsigned u = *(const unsigned*)&Kb[base];
    float x1 = bf2f((bf_t)(u & 0xFFFF)), x2 = bf2f((bf_t)(u >> 16));
    unsigned o = (unsigned)f2bf(x1 * cv - x2 * sv) | ((unsigned)f2bf(x1 * sv + x2 * cv) << 16);
    *(unsigned*)&Kb[base] = o;
  }
}

// ---------------------------------------------------------------------------
// Causal flash attention, in-block split-KV, SWAPPED operands.
// S^T = mfma(K,Q): lane col = q-row -> softmax is lane-local (2 shfl/mi for
// the cross-kg reduce). O^T = mfma(V,P): accumulator col = q -> rescale is
// lane-local. P goes through wave-private LDS in the standard [row][k]
// B-operand convention (layout-safe). 4 waves split KV; merge via LDS.
// ---------------------------------------------------------------------------
__global__ __launch_bounds__(256) void attn_kernel(const bf_t* __restrict__ Qb,
                                                   const bf_t* __restrict__ Kb,
                                                   const bf_t* __restrict__ Vt,
                                                   bf_t* __restrict__ AO) {
  const int t = threadIdx.x;
  const int lane = t & 63;
  const int w = t >> 6;
  const int col = lane & 15;
  const int kg = lane >> 4;
  const int bh = blockIdx.y;
  const int q0 = ((int)gridDim.x - 1 - (int)blockIdx.x) * 64;
  const bf_t* Qp = Qb + (size_t)bh * 2048 * 64;
  const bf_t* Kp = Kb + (size_t)bh * 2048 * 64;
  const bf_t* Vp = Vt + (size_t)bh * 64 * 2048;

  // LDS: [0,20480) per-wave Pl (4 x [64 q][40] bf16), overlaid post-loop by
  // ocomb f32[64][65]. [20480,21504) mw f32[4][64]. [21504,22528) lw.
  __shared__ char sh[22528];
  bf_t* Plw = (bf_t*)sh + w * 2560;
  float* ocomb = (float*)sh;                 // [64][65]
  float* mw = (float*)(sh + 20480);          // [4][64]
  float* lw = (float*)(sh + 21504);          // [4][64]

  s16x8 qf[4][2];
#pragma unroll
  for (int mi = 0; mi < 4; ++mi)
#pragma unroll
    for (int ks = 0; ks < 2; ++ks)
      qf[mi][ks] = ld_frag(Qp + (size_t)(q0 + mi * 16 + col) * 64 + ks * 32 + kg * 8);

  f32x4 o[4][4] = {};  // [ni(d)][mi(q)]; C: row=d-sub(kg*4+r), col=q
  float mrun[4], lrun[4];  // per mi, q = q0+mi*16+col (lane-local)
#pragma unroll
  for (int mi = 0; mi < 4; ++mi) {
    mrun[mi] = -INFINITY;
    lrun[mi] = 0.0f;
  }

  for (int kb = w * 32; kb < q0 + 64; kb += 128) {
    s16x8 kf[2][2];
#pragma unroll
    for (int nk = 0; nk < 2; ++nk)
#pragma unroll
      for (int ks = 0; ks < 2; ++ks)
        kf[nk][ks] = ld_frag(Kp + (size_t)(kb + nk * 16 + col) * 64 + ks * 32 + kg * 8);

    // S^T: A=K (M=key), B=Q (N=q). C: row=key kg*4+r, col=q.
    f32x4 sc[4][2] = {};
#pragma unroll
    for (int mi = 0; mi < 4; ++mi)
#pragma unroll
      for (int nk = 0; nk < 2; ++nk)
#pragma unroll
        for (int ks = 0; ks < 2; ++ks)
          sc[mi][nk] = MFMA(kf[nk][ks], qf[mi][ks], sc[mi][nk]);

#pragma unroll
    for (int mi = 0; mi < 4; ++mi) {
      const int qg = q0 + mi * 16 + col;
      const int kbase = kb + kg * 4;
      float ev[2][4];
      float mx = -INFINITY;
#pragma unroll
      for (int nk = 0; nk < 2; ++nk)
#pragma unroll
        for (int r = 0; r < 4; ++r) {
          float s = (kbase + nk * 16 + r <= qg) ? sc[mi][nk][r] * 0.125f : -INFINITY;
          ev[nk][r] = s;
          mx = fmaxf(mx, s);
        }
      // cross-kg (lanes col, col+16, col+32, col+48) reduce: 2 shfl
      mx = fmaxf(mx, __shfl_xor(mx, 16));
      mx = fmaxf(mx, __shfl_xor(mx, 32));
      float mold = mrun[mi];
      float mn = fmaxf(mold, mx);
      // fully-masked split tile: mn=-inf; clamp so exp(-inf - mnc)=0, no NaN
      float mnc = fmaxf(mn, -1e30f);
      float a = __expf(mold - mnc);
      float rs = 0.0f;
#pragma unroll
      for (int nk = 0; nk < 2; ++nk)
#pragma unroll
        for (int r = 0; r < 4; ++r) {
          float e = __expf(ev[nk][r] - mnc);
          ev[nk][r] = e;
          rs += e;
        }
      rs += __shfl_xor(rs, 16);
      rs += __shfl_xor(rs, 32);
      lrun[mi] = lrun[mi] * a + rs;
      mrun[mi] = mn;
#pragma unroll
      for (int ni = 0; ni < 4; ++ni)
#pragma unroll
        for (int r = 0; r < 4; ++r) o[ni][mi][r] *= a;
      // write P[q][key] (bf16) — standard [row][k] convention, 8B stores
#pragma unroll
      for (int nk = 0; nk < 2; ++nk) {
        s16x4 p;
        p[0] = (short)f2bf(ev[nk][0]);
        p[1] = (short)f2bf(ev[nk][1]);
        p[2] = (short)f2bf(ev[nk][2]);
        p[3] = (short)f2bf(ev[nk][3]);
        *(s16x4*)&Plw[(mi * 16 + col) * 40 + nk * 16 + kg * 4] = p;
      }
    }

    // O^T += V^T x P^T: A=V (M=d), B=P (N=q). Same-wave lgkmcnt orders Pl.
    s16x8 pa[4], vf[4];
#pragma unroll
    for (int mi = 0; mi < 4; ++mi) pa[mi] = ld_frag(&Plw[(mi * 16 + col) * 40 + kg * 8]);
#pragma unroll
    for (int ni = 0; ni < 4; ++ni)
      vf[ni] = ld_frag(Vp + (size_t)(ni * 16 + col) * 2048 + kb + kg * 8);
#pragma unroll
    for (int ni = 0; ni < 4; ++ni)
#pragma unroll
      for (int mi = 0; mi < 4; ++mi) o[ni][mi] = MFMA(vf[ni], pa[mi], o[ni][mi]);
  }

  // ---- merge the 4 waves' partial (m, l, O) ----
  if (kg == 0) {
#pragma unroll
    for (int mi = 0; mi < 4; ++mi) {
      int row = mi * 16 + col;
      mw[w * 64 + row] = mrun[mi];
      lw[w * 64 + row] = lrun[mi];
    }
  }
  __syncthreads();  // all k-loops done; Pl dead; stats visible

  for (int i = t; i < 64 * 65; i += 256) ocomb[i] = 0.0f;
  __syncthreads();

  // accumulate scaled O^T into ocomb[q][d]; scale s is lane-local (col=q)
#pragma unroll
  for (int mi = 0; mi < 4; ++mi) {
    int row = mi * 16 + col;
    float ms = fmaxf(fmaxf(mw[row], mw[64 + row]), fmaxf(mw[128 + row], mw[192 + row]));
    float mo = mrun[mi];
    float s = (mo == -INFINITY) ? 0.0f : __expf(mo - ms);
#pragma unroll
    for (int ni = 0; ni < 4; ++ni)
#pragma unroll
      for (int r = 0; r < 4; ++r)
        atomicAdd(&ocomb[row * 65 + ni * 16 + kg * 4 + r], o[ni][mi][r] * s);
  }
  __syncthreads();

  // output: wave w writes row stripe [16w, 16w+16), coalesced along d
  const int b = bh >> 4, h = bh & 15;
#pragma unroll
  for (int r = 0; r < 4; ++r) {
    int row = w * 16 + kg * 4 + r;
    float ms = fmaxf(fmaxf(mw[row], mw[64 + row]), fmaxf(mw[128 + row], mw[192 + row]));
    float ls = 0.0f;
#pragma unroll
    for (int w2 = 0; w2 < 4; ++w2) {
      float mv = mw[w2 * 64 + row];
      ls += (mv == -INFINITY) ? 0.0f : lw[w2 * 64 + row] * __expf(mv - ms);
    }
    float inv = 1.0f / ls;
    int qg = q0 + row;
#pragma unroll
    for (int ni = 0; ni < 4; ++ni)
      AO[((size_t)b * 2048 + qg) * 1024 + h * 64 + ni * 16 + col] =
          f2bf(ocomb[row * 65 + ni * 16 + col] * inv);
  }
}

// ---------------------------------------------------------------------------
extern "C" void kernel_launch(void* const* d_in, const int* in_sizes, int n_in,
                              void* d_out, int out_size, void* d_ws, size_t ws_size,
                              hipStream_t stream) {
  const float* x = (const float*)d_in[0];
  const int* pos = (const int*)d_in[1];
  const float* Wq = (const float*)d_in[2];
  const float* Wk = (const float*)d_in[3];
  const float* Wv = (const float*)d_in[4];
  const float* Wo = (const float*)d_in[5];
  float* out = (float*)d_out;

  char* ws = (char*)d_ws;
  bf_t* xb    = (bf_t*)(ws);                 //  8,388,608 B  [4096][1024]
  bf_t* Wqkvb = (bf_t*)(ws + 8388608);       //  6,291,456 B  [3072][1024]
  bf_t* Wob   = (bf_t*)(ws + 14680064);      //  2,097,152 B  [1024][1024]
  bf_t* Qb    = (bf_t*)(ws + 16777216);      //  8,388,608 B  [2][16][2048][64]
  bf_t* Kb    = (bf_t*)(ws + 25165824);      //  8,388,608 B  [2][16][2048][64]
  bf_t* Vt    = (bf_t*)(ws + 33554432);      //  8,388,608 B  [2][16][64][2048]
  bf_t* AO    = (bf_t*)(ws + 41943040);      //  8,388,608 B  [4096][1024]

  cvt_kernel<<<4096, 256, 0, stream>>>(x, xb, 1048576);
  cvt_kernel<<<1024, 256, 0, stream>>>(Wq, Wqkvb, 262144);
  cvt_kernel<<<1024, 256, 0, stream>>>(Wk, Wqkvb + 1048576, 262144);
  cvt_kernel<<<1024, 256, 0, stream>>>(Wv, Wqkvb + 2097152, 262144);
  cvt_kernel<<<1024, 256, 0, stream>>>(Wo, Wob, 262144);

  gemm_kernel<0><<<dim3(24, 32), 256, 0, stream>>>(xb, Wqkvb, nullptr, Qb, Kb, Vt,
                                                   4096, 3072, 1024);
  rope_kernel<<<8192, 256, 0, stream>>>(Qb, Kb, pos, 2097152);
  attn_kernel<<<dim3(32, 32), 256, 0, stream>>>(Qb, Kb, Vt, AO);
  gemm_kernel<1><<<dim3(8, 32), 256, 0, stream>>>(AO, Wob, out, nullptr, nullptr, nullptr,
                                                  4096, 1024, 1024);
}